// Round 6
// baseline (499.959 us; speedup 1.0000x reference)
//
#include <hip/hip_runtime.h>
#include <hip/hip_bf16.h>
#include <math.h>

#define BB 16
#define LL 512
#define HH 256
#define NHEAD 8
#define HDIM 32
#define LP1 513
#define NHHD 256
#define NODES_ELEMS (BB*LL*HH)

typedef __attribute__((ext_vector_type(8))) short bf16x8;
typedef __attribute__((ext_vector_type(4))) float f32x4;

__device__ __forceinline__ unsigned short f2bf(float f) {
  union { float f; unsigned u; } x; x.f = f;
  unsigned r = x.u + 0x7fffu + ((x.u >> 16) & 1u);
  return (unsigned short)(r >> 16);
}
__device__ __forceinline__ float bf2f(unsigned short u) {
  union { unsigned u; float f; } x; x.u = (unsigned)u << 16; return x.f;
}

// ---------------------------------------------------------------------------
__global__ __launch_bounds__(256) void transpose_kernel(const float* __restrict__ in,
                                                        float* __restrict__ out,
                                                        int R, int C) {
  int idx = blockIdx.x * 256 + threadIdx.x;
  if (idx < R * C) {
    int r = idx / C, c = idx % C;
    out[(size_t)c * R + r] = in[idx];
  }
}

__global__ __launch_bounds__(256) void cvt_bf16_kernel(const float* __restrict__ in,
                                                       unsigned short* __restrict__ out,
                                                       int n) {
  int idx = blockIdx.x * 256 + threadIdx.x;
  if (idx < n) out[idx] = f2bf(in[idx]);
}

// edge -> packed bits: ep[row*64+lane] bit u = edge[row][lane+64u] > 0
__global__ __launch_bounds__(256) void edge_pack_kernel(const int* __restrict__ edge,
                                                        unsigned char* __restrict__ ep) {
  int row = blockIdx.x * 4 + (threadIdx.x >> 6);
  int lane = threadIdx.x & 63;
  const int* adj = edge + ((size_t)row << 9);
  unsigned v = 0;
#pragma unroll
  for (int u = 0; u < 8; u++) v |= (adj[lane + 64 * u] > 0 ? 1u : 0u) << u;
  ep[((size_t)row << 6) + lane] = (unsigned char)v;
}

// fc_w [256 k][256 o] -> fcwT[o][k] bf16
__global__ __launch_bounds__(256) void fcwT_kernel(const float* __restrict__ in,
                                                   unsigned short* __restrict__ out) {
  int idx = blockIdx.x * 256 + threadIdx.x;
  int o = idx >> 8, k = idx & 255;
  out[idx] = f2bf(in[k * 256 + o]);
}

// Bcat M1 part: Bcat[(n*32+d)*512 + k] = sum_c WQw[n][c][k] * Fw[n][c][d]
__global__ __launch_bounds__(256) void bcat_m1_kernel(const float* __restrict__ WQw,
                                                      const float* __restrict__ fcw,
                                                      unsigned short* __restrict__ Bcat) {
  __shared__ float wq_s[256][16];
  __shared__ float fw_s[256][32];
  int n = blockIdx.x >> 4, kt = blockIdx.x & 15;
  int t = threadIdx.x;
#pragma unroll
  for (int i = 0; i < 16; i++) {
    int c = i * 16 + (t >> 4), kk = t & 15;
    wq_s[c][kk] = WQw[(size_t)n * 65536 + c * 256 + kt * 16 + kk];
  }
#pragma unroll
  for (int i = 0; i < 32; i++) {
    int idx = i * 256 + t;
    fw_s[idx >> 5][idx & 31] = fcw[(size_t)n * 24576 + idx];
  }
  __syncthreads();
  int kloc = t >> 4, dp = t & 15;
  float a0 = 0.f, a1v = 0.f;
  for (int c = 0; c < 256; c++) {
    float wv = wq_s[c][kloc];
    a0 = fmaf(wv, fw_s[c][dp * 2], a0);
    a1v = fmaf(wv, fw_s[c][dp * 2 + 1], a1v);
  }
  int k = kt * 16 + kloc;
  Bcat[((size_t)n * 32 + dp * 2) * 512 + k] = f2bf(a0);
  Bcat[((size_t)n * 32 + dp * 2 + 1) * 512 + k] = f2bf(a1v);
}

// Bcat data half: Bcat[(n*32+d)*512 + 256 + c] = Fw[n][256+2c][d]
__global__ __launch_bounds__(256) void bcat_m2_kernel(const float* __restrict__ fcw,
                                                      unsigned short* __restrict__ Bcat) {
  int idx = blockIdx.x * 256 + threadIdx.x;
  int n = idx >> 13, d = (idx >> 8) & 31, c = idx & 255;
  Bcat[((size_t)n * 32 + d) * 512 + 256 + c] =
      f2bf(fcw[((size_t)n * 768 + 256 + 2 * c) * 32 + d]);
}

// bqf[n][d] = sum_c WQb[n][c] * Fw[n][c][d]
__global__ __launch_bounds__(32) void bqf_kernel(const float* __restrict__ WQb,
                                                 const float* __restrict__ fcw,
                                                 float* __restrict__ bqf) {
  int n = blockIdx.x, d = threadIdx.x;
  float s = 0.f;
  for (int c = 0; c < 256; c++)
    s = fmaf(WQb[n * 256 + c], fcw[((size_t)n * 768 + c) * 32 + d], s);
  bqf[n * 32 + d] = s;
}

// w1/w2/c1/c2 folded attention weights
__global__ __launch_bounds__(256) void w12_kernel(const float* __restrict__ WQw,
                                                  const float* __restrict__ WQb,
                                                  const float* __restrict__ a1,
                                                  const float* __restrict__ a2,
                                                  float* __restrict__ w1,
                                                  float* __restrict__ w2,
                                                  float* __restrict__ c1,
                                                  float* __restrict__ c2) {
  int n = blockIdx.x, t = threadIdx.x;
  float s1 = 0.f, s2 = 0.f;
  for (int c = 0; c < 256; c++) {
    float wv = WQw[((size_t)(n * 256 + c)) * 256 + t];
    s1 = fmaf(a1[n * 768 + c], wv, s1);
    s2 = fmaf(a2[n * 768 + c], wv, s2);
  }
  w1[n * 256 + t] = s1;
  w2[n * 256 + t] = s2;
  __shared__ float r1[256], r2[256];
  r1[t] = a1[n * 768 + t] * WQb[n * 256 + t];
  r2[t] = a2[n * 768 + t] * WQb[n * 256 + t];
  __syncthreads();
  for (int o = 128; o; o >>= 1) {
    if (t < o) { r1[t] += r1[t + o]; r2[t] += r2[t + o]; }
    __syncthreads();
  }
  if (t == 0) { c1[n] = r1[0]; c2[n] = r2[0]; }
}

// ---------------------------------------------------------------------------
// Shared post-processing once a relay row is produced (one block per batch b):
// stores relay fp32, yb bf16 row; if do_extras: ra1/ra2, rf(+fcb+bqf), qst.
__device__ __forceinline__ void relay_post(
    int b, int t, float relval,
    const float* __restrict__ a1, const float* __restrict__ a2,
    const float* __restrict__ fcw, const float* __restrict__ fcb,
    const float* __restrict__ bqf,
    const float* __restrict__ sqTn, const float* __restrict__ sqbn,
    int do_extras,
    float* __restrict__ ra1, float* __restrict__ ra2,
    float* __restrict__ rf, float* __restrict__ qst,
    unsigned short* __restrict__ yb, float* __restrict__ relay,
    float* rel, float* red, float* pf) {
  relay[b * 256 + t] = relval;
  yb[((size_t)b * LP1) * 256 + t] = f2bf(relval);
  rel[t] = relval;
  __syncthreads();
  if (!do_extras) return;
  int lane = t & 63, w = t >> 6;
  // qst row for next iteration
  float q = 0.f;
  for (int k = 0; k < 256; k++) q = fmaf(rel[k], sqTn[(size_t)k * 256 + t], q);
  qst[b * 256 + t] = q + sqbn[t];
  for (int n = 0; n < 8; n++) {
    float p1 = rel[t] * a1[n * 768 + 257 + 2 * t];
    float p2 = rel[t] * a2[n * 768 + 257 + 2 * t];
#pragma unroll
    for (int o = 32; o; o >>= 1) { p1 += __shfl_xor(p1, o); p2 += __shfl_xor(p2, o); }
    if (lane == 0) { red[w] = p1; red[4 + w] = p2; }
    int d = t & 31, seg = t >> 5;
    float s = 0.f;
    for (int u = 0; u < 32; u++) {
      int k = seg * 32 + u;
      s = fmaf(rel[k], fcw[((size_t)n * 768 + 257 + 2 * k) * 32 + d], s);
    }
    pf[seg * 33 + d] = s;
    __syncthreads();
    if (t == 0) {
      ra1[n * 16 + b] = red[0] + red[1] + red[2] + red[3];
      ra2[n * 16 + b] = red[4] + red[5] + red[6] + red[7];
    }
    if (t < 32) {
      float ss = 0.f;
      for (int gg = 0; gg < 8; gg++) ss += pf[gg * 33 + t];
      rf[((size_t)n * 16 + b) * 32 + t] = ss + fcb[n * 32 + t] + bqf[n * 32 + t];
    }
    __syncthreads();
  }
}

// relay = mean_L(data), then extras for it=0
__global__ __launch_bounds__(256) void relay_init_kernel(
    const float* __restrict__ data,
    const float* __restrict__ a1, const float* __restrict__ a2,
    const float* __restrict__ fcw, const float* __restrict__ fcb,
    const float* __restrict__ bqf,
    const float* __restrict__ sqTn, const float* __restrict__ sqbn,
    float* __restrict__ ra1, float* __restrict__ ra2,
    float* __restrict__ rf, float* __restrict__ qst,
    unsigned short* __restrict__ yb, float* __restrict__ relay) {
  __shared__ float rel[256];
  __shared__ float red[8];
  __shared__ float pf[8 * 33];
  int b = blockIdx.x, t = threadIdx.x;
  float s = 0.f;
  const float* p = data + (size_t)b * LL * HH + t;
  for (int l = 0; l < LL; l++) s += p[(size_t)l * HH];
  relay_post(b, t, s * (1.0f / 512.0f), a1, a2, fcw, fcb, bqf, sqTn, sqbn, 1,
             ra1, ra2, rf, qst, yb, relay, rel, red, pf);
}

// relay = lrelu(atts @ soT + sob), then extras for next iter
__global__ __launch_bounds__(256) void relay_update_kernel(
    const float* __restrict__ atts,
    const float* __restrict__ soT_it, const float* __restrict__ sob_it,
    const float* __restrict__ a1, const float* __restrict__ a2,
    const float* __restrict__ fcw, const float* __restrict__ fcb,
    const float* __restrict__ bqf,
    const float* __restrict__ sqTn, const float* __restrict__ sqbn,
    int do_extras,
    float* __restrict__ ra1, float* __restrict__ ra2,
    float* __restrict__ rf, float* __restrict__ qst,
    unsigned short* __restrict__ yb, float* __restrict__ relay) {
  __shared__ float rel[256];
  __shared__ float red[8];
  __shared__ float pf[8 * 33];
  __shared__ float xr[256];
  int b = blockIdx.x, t = threadIdx.x;
  xr[t] = atts[b * 256 + t];
  __syncthreads();
  float acc = 0.f;
  for (int k = 0; k < 256; k++) acc = fmaf(xr[k], soT_it[(size_t)k * 256 + t], acc);
  float v = acc + sob_it[t];
  v = v > 0.f ? v : 0.01f * v;
  relay_post(b, t, v, a1, a2, fcw, fcb, bqf, sqTn, sqbn, do_extras,
             ra1, ra2, rf, qst, yb, relay, rel, red, pf);
}

// ---------------------------------------------------------------------------
// Fused LayerNorm + ei/ej: one wave per row; writes xnb bf16 + ei/ej all heads
__global__ __launch_bounds__(256) void lnei_kernel(const float* __restrict__ nodes,
                                                   const float* __restrict__ data,
                                                   const float* __restrict__ g,
                                                   const float* __restrict__ bb,
                                                   const float* __restrict__ w1,
                                                   const float* __restrict__ w2,
                                                   const float* __restrict__ a1,
                                                   const float* __restrict__ a2,
                                                   const float* __restrict__ c1,
                                                   const float* __restrict__ c2,
                                                   const float* __restrict__ ra1,
                                                   const float* __restrict__ ra2,
                                                   unsigned short* __restrict__ xnb,
                                                   float* __restrict__ ei,
                                                   float* __restrict__ ej) {
  int r = blockIdx.x * 4 + (threadIdx.x >> 6);
  int b = r >> 9;
  int lane = threadIdx.x & 63;
  float x[4], dv[4];
#pragma unroll
  for (int u = 0; u < 4; u++) {
    int c = lane + 64 * u;
    x[u] = nodes[(size_t)r * 256 + c];
    dv[u] = data[(size_t)r * 256 + c];
  }
  float s = x[0] + x[1] + x[2] + x[3];
#pragma unroll
  for (int o = 32; o; o >>= 1) s += __shfl_xor(s, o);
  float mean = s * (1.0f / 256.0f);
  float v = 0.f;
#pragma unroll
  for (int u = 0; u < 4; u++) { x[u] -= mean; v = fmaf(x[u], x[u], v); }
#pragma unroll
  for (int o = 32; o; o >>= 1) v += __shfl_xor(v, o);
  float rstd = rsqrtf(v * (1.0f / 256.0f) + 1e-5f);
  float xv[4];
#pragma unroll
  for (int u = 0; u < 4; u++) {
    int c = lane + 64 * u;
    xv[u] = x[u] * rstd * g[c] + bb[c];
    xnb[(size_t)r * 256 + c] = f2bf(xv[u]);
  }
  for (int n = 0; n < 8; n++) {
    float s1 = 0.f, s2 = 0.f;
#pragma unroll
    for (int u = 0; u < 4; u++) {
      int c = lane + 64 * u;
      s1 = fmaf(xv[u], w1[n * 256 + c], s1);
      s1 = fmaf(dv[u], a1[n * 768 + 256 + 2 * c], s1);
      s2 = fmaf(xv[u], w2[n * 256 + c], s2);
      s2 = fmaf(dv[u], a2[n * 768 + 256 + 2 * c], s2);
    }
#pragma unroll
    for (int o = 32; o; o >>= 1) { s1 += __shfl_xor(s1, o); s2 += __shfl_xor(s2, o); }
    if (lane == 0) {
      ei[n * 8192 + r] = s1 + c1[n] + ra1[n * 16 + b];
      ej[n * 8192 + r] = s2 + c2[n] + ra2[n * 16 + b];
    }
  }
}

// ---------------------------------------------------------------------------
// G-GEMM: GT[n][b][d][j] = [xn ; data](row j) @ Bcat col (n*32+d).  K=512 dual-A.
__global__ __launch_bounds__(256) void g_gemm_kernel(
    const unsigned short* __restrict__ A1, const unsigned short* __restrict__ A2,
    const unsigned short* __restrict__ Bcat, unsigned short* __restrict__ GT) {
  int tileN = blockIdx.x * 64;
  int tileM = blockIdx.y * 128;
  int t = threadIdx.x;
  int wv = t >> 6, lane = t & 63;
  int lo = lane & 15, quad = lane >> 4;
  int rowBase0 = tileM + wv * 32;
  const unsigned short* ap1[2];
  const unsigned short* ap2[2];
#pragma unroll
  for (int rt = 0; rt < 2; rt++) {
    int arow = rowBase0 + rt * 16 + lo;
    ap1[rt] = A1 + (size_t)arow * 256 + quad * 8;
    ap2[rt] = A2 + (size_t)arow * 256 + quad * 8;
  }
  f32x4 acc[2][4] = {};
  for (int k0 = 0; k0 < 512; k0 += 32) {
    bf16x8 af[2];
#pragma unroll
    for (int rt = 0; rt < 2; rt++)
      af[rt] = (k0 < 256) ? *(const bf16x8*)(ap1[rt] + k0)
                          : *(const bf16x8*)(ap2[rt] + k0 - 256);
#pragma unroll
    for (int ct = 0; ct < 4; ct++) {
      bf16x8 bf_ = *(const bf16x8*)(Bcat + (size_t)(tileN + ct * 16 + lo) * 512 + k0 + quad * 8);
#pragma unroll
      for (int rt = 0; rt < 2; rt++)
        acc[rt][ct] = __builtin_amdgcn_mfma_f32_16x16x32_bf16(af[rt], bf_, acc[rt][ct], 0, 0, 0);
    }
  }
#pragma unroll
  for (int rt = 0; rt < 2; rt++) {
#pragma unroll
    for (int ct = 0; ct < 4; ct++) {
      int co = tileN + ct * 16 + lo;
      int n = co >> 5, d = co & 31;
      int jrow = rowBase0 + rt * 16 + quad * 4;
      int b2 = jrow >> 9, jj = jrow & 511;
      ushort4 pk;
      pk.x = f2bf(acc[rt][ct][0]);
      pk.y = f2bf(acc[rt][ct][1]);
      pk.z = f2bf(acc[rt][ct][2]);
      pk.w = f2bf(acc[rt][ct][3]);
      *(ushort4*)&GT[(((size_t)(n * 16 + b2) * 32 + d) << 9) + jj] = pk;
    }
  }
}

// ---------------------------------------------------------------------------
// MFMA GEMM over K=256 bf16, M-tile 128, N-tile 64
// mode 1: fc epilogue (nodes fp32 + yb bf16); mode 2: bf16 out (kt)
__global__ __launch_bounds__(256) void mfma_gemm_kernel(
    const unsigned short* __restrict__ A, const unsigned short* __restrict__ Bw,
    const float* __restrict__ bias, int Mvalid, int mode,
    float* __restrict__ outF, unsigned short* __restrict__ outB,
    const float* __restrict__ resid, const int* __restrict__ mask,
    unsigned short* __restrict__ yb) {
  int tileN = blockIdx.x * 64;
  int tileM = blockIdx.y * 128;
  int t = threadIdx.x;
  int wv = t >> 6, lane = t & 63;
  int lo = lane & 15, quad = lane >> 4;
  int rowBase0 = tileM + wv * 32;
  const unsigned short* aptr[2];
#pragma unroll
  for (int rt = 0; rt < 2; rt++) {
    int arow = rowBase0 + rt * 16 + lo;
    if (arow >= Mvalid) arow = Mvalid - 1;
    aptr[rt] = A + (size_t)arow * 256 + quad * 8;
  }
  f32x4 acc[2][4] = {};
  for (int k0 = 0; k0 < 256; k0 += 32) {
    bf16x8 af[2];
#pragma unroll
    for (int rt = 0; rt < 2; rt++) af[rt] = *(const bf16x8*)(aptr[rt] + k0);
#pragma unroll
    for (int ct = 0; ct < 4; ct++) {
      bf16x8 bf_ = *(const bf16x8*)(Bw + (size_t)(tileN + ct * 16 + lo) * 256 + k0 + quad * 8);
#pragma unroll
      for (int rt = 0; rt < 2; rt++)
        acc[rt][ct] = __builtin_amdgcn_mfma_f32_16x16x32_bf16(af[rt], bf_, acc[rt][ct], 0, 0, 0);
    }
  }
#pragma unroll
  for (int rt = 0; rt < 2; rt++) {
    int rowBase = rowBase0 + rt * 16;
#pragma unroll
    for (int ct = 0; ct < 4; ct++) {
      int co = tileN + ct * 16 + lo;
      float bv = bias[co];
#pragma unroll
      for (int r = 0; r < 4; r++) {
        int row = rowBase + quad * 4 + r;
        if (row >= Mvalid) continue;
        float v = acc[rt][ct][r] + bv;
        if (mode == 1) {
          v = v > 0.f ? v : 0.01f * v;
          v = (mask[row] != 0) ? resid[(size_t)row * 256 + co] + v : 0.f;
          outF[(size_t)row * 256 + co] = v;
          yb[((size_t)(row + (row >> 9) + 1)) * 256 + co] = f2bf(v);
        } else {
          outB[(size_t)row * 256 + co] = f2bf(v);
        }
      }
    }
  }
}

// ---------------------------------------------------------------------------
// GAT: softmax (packed-edge) -> tiny MFMA aggregation vs pre-projected GT
__global__ __launch_bounds__(256) void gat_agg_kernel(
    const unsigned short* __restrict__ GT,    // [8][16][32][512] bf16
    const float* __restrict__ ei, const float* __restrict__ ej,
    const unsigned char* __restrict__ ep,     // [8192][64] packed adj bits
    const float* __restrict__ rf,             // rf + fcb + bqf folded
    unsigned short* __restrict__ tempb) {     // [8192][256] bf16
  __shared__ unsigned short W[32][512];
  int blk = blockIdx.x;
  int n = blk >> 8;
  int b = (blk >> 4) & 15;
  int i0 = (blk & 15) << 5;
  int t = threadIdx.x;
  int wv = t >> 6, lane = t & 63;
  int lo = lane & 15, quad = lane >> 4;

  const float* ejrow = ej + n * 8192 + b * 512;
  float ejv[8];
#pragma unroll
  for (int u = 0; u < 8; u++) ejv[u] = ejrow[lane + 64 * u];
  for (int rr = 0; rr < 8; rr++) {
    int row = wv * 8 + rr;
    float eiv = ei[n * 8192 + b * 512 + i0 + row];
    unsigned pb = ep[(((size_t)(b * 512 + i0 + row)) << 6) + lane];
    float evv[8];
    float m = -3.0e38f;
#pragma unroll
    for (int u = 0; u < 8; u++) {
      float e;
      if ((pb >> u) & 1) { e = eiv + ejv[u]; e = e > 0.f ? e : 0.2f * e; }
      else e = -9.0e15f;
      evv[u] = e;
      m = fmaxf(m, e);
    }
#pragma unroll
    for (int o = 32; o; o >>= 1) m = fmaxf(m, __shfl_xor(m, o));
    float s = 0.f;
#pragma unroll
    for (int u = 0; u < 8; u++) {
      float wexp = __expf(evv[u] - m);
      evv[u] = wexp;
      s += wexp;
    }
#pragma unroll
    for (int o = 32; o; o >>= 1) s += __shfl_xor(s, o);
    float inv = 1.0f / s;
    int rx = (row & 7) << 3;
#pragma unroll
    for (int u = 0; u < 8; u++) {
      int col = lane + 64 * u;
      W[row][((col >> 3 << 3) ^ rx) + (col & 7)] = f2bf(evv[u] * inv);
    }
  }
  __syncthreads();

  int rt = wv >> 1, dh = wv & 1;
  int arow = rt * 16 + lo;
  int rx = arow & 7;
  const unsigned short* gtb = GT + (((size_t)(n * 16 + b) * 32) << 9);
  f32x4 acc = {};
  for (int k0 = 0; k0 < 512; k0 += 32) {
    int chunk = (k0 >> 3) + quad;
    bf16x8 a0 = *(const bf16x8*)&W[arow][(chunk ^ rx) << 3];
    bf16x8 bf_ = *(const bf16x8*)(gtb + (((size_t)(dh * 16 + lo)) << 9) + k0 + quad * 8);
    acc = __builtin_amdgcn_mfma_f32_16x16x32_bf16(a0, bf_, acc, 0, 0, 0);
  }
  int d = dh * 16 + lo;
  float base = rf[((size_t)n * 16 + b) * 32 + d];
#pragma unroll
  for (int r = 0; r < 4; r++) {
    int row = rt * 16 + quad * 4 + r;
    float v = acc[r] + base;
    v = v > 0.f ? v : expm1f(v);
    tempb[((size_t)(b * 512 + i0 + row)) * 256 + n * 32 + d] = f2bf(v);
  }
}

// ---------------------------------------------------------------------------
// star attention on bf16 kt
__global__ __launch_bounds__(256) void star_attn_kernel(const float* __restrict__ qstar,
                                                        const unsigned short* __restrict__ ktb,
                                                        const int* __restrict__ mask,
                                                        float* __restrict__ attstar) {
  int b = blockIdx.x >> 3, n = blockIdx.x & 7;
  int t = threadIdx.x;
  int lane = t & 63, w = t >> 6;
  __shared__ float qv[32];
  __shared__ float pre[LP1];
  __shared__ float red[4];
  __shared__ float par[8][33];
  if (t < 32) qv[t] = qstar[b * 256 + n * 32 + t];
  __syncthreads();
  const float scale = 0.17677669529663687f;
  for (int l = t; l < LP1; l += 256) {
    bool masked = (l > 0) && (mask[b * LL + l - 1] == 0);
    float p;
    if (masked) p = -3.4e38f;
    else {
      p = 0.f;
      const unsigned short* krow = ktb + ((size_t)b * LP1 + l) * 256 + n * 32;
#pragma unroll
      for (int d = 0; d < 32; d++) p = fmaf(qv[d], bf2f(krow[d]), p);
      p *= scale;
    }
    pre[l] = p;
  }
  __syncthreads();
  float m = -3.4e38f;
  for (int l = t; l < LP1; l += 256) m = fmaxf(m, pre[l]);
#pragma unroll
  for (int o = 32; o; o >>= 1) m = fmaxf(m, __shfl_xor(m, o));
  if (lane == 0) red[w] = m;
  __syncthreads();
  m = fmaxf(fmaxf(red[0], red[1]), fmaxf(red[2], red[3]));
  __syncthreads();
  float s = 0.f;
  for (int l = t; l < LP1; l += 256) {
    float wv = __expf(pre[l] - m);
    pre[l] = wv;
    s += wv;
  }
#pragma unroll
  for (int o = 32; o; o >>= 1) s += __shfl_xor(s, o);
  if (lane == 0) red[w] = s;
  __syncthreads();
  float denom = red[0] + red[1] + red[2] + red[3];
  int d = t & 31, g = t >> 5;
  float acc = 0.f;
  for (int l = g; l < LP1; l += 8)
    acc = fmaf(pre[l], bf2f(ktb[((size_t)b * LP1 + l) * 256 + n * 32 + d]), acc);
  par[g][d] = acc;
  __syncthreads();
  if (t < 32) {
    float a = 0.f;
    for (int gg = 0; gg < 8; gg++) a += par[gg][t];
    attstar[b * 256 + n * 32 + t] = a / denom;
  }
}

// ---------------------------------------------------------------------------
extern "C" void kernel_launch(void* const* d_in, const int* in_sizes, int n_in,
                              void* d_out, int out_size, void* d_ws, size_t ws_size,
                              hipStream_t stream) {
  const float* data  = (const float*)d_in[0];
  const float* WQw   = (const float*)d_in[1];
  const float* WQb   = (const float*)d_in[2];
  const float* a1    = (const float*)d_in[3];
  const float* a2    = (const float*)d_in[4];
  const float* fcw_g = (const float*)d_in[5];
  const float* fcb_g = (const float*)d_in[6];
  const float* ng    = (const float*)d_in[7];
  const float* nb    = (const float*)d_in[8];
  const float* sq_w  = (const float*)d_in[9];
  const float* sq_b  = (const float*)d_in[10];
  const float* sk_w  = (const float*)d_in[11];
  const float* sk_b  = (const float*)d_in[12];
  const float* so_w  = (const float*)d_in[13];
  const float* so_b  = (const float*)d_in[14];
  const float* fc_w  = (const float*)d_in[15];
  const float* fc_b  = (const float*)d_in[16];
  const int*   mask  = (const int*)d_in[17];
  const int*   edge  = (const int*)d_in[18];

  float* nodes = (float*)d_out;
  float* relay = nodes + NODES_ELEMS;

  char* p = (char*)d_ws;
  auto alloc = [&](size_t bytes) -> char* {
    char* r = p; p += (bytes + 255) & ~(size_t)255; return r;
  };
  unsigned short* xnb  = (unsigned short*)alloc((size_t)8192 * 256 * 2);
  unsigned short* datab= (unsigned short*)alloc((size_t)8192 * 256 * 2);
  unsigned short* GT   = (unsigned short*)alloc((size_t)8 * 16 * 32 * 512 * 2);
  unsigned short* tmpb = (unsigned short*)alloc((size_t)8192 * 256 * 2);
  unsigned short* yb   = (unsigned short*)alloc((size_t)8208 * 256 * 2);
  unsigned short* ktb  = (unsigned short*)alloc((size_t)8208 * 256 * 2);
  unsigned char* ep    = (unsigned char*)alloc((size_t)8192 * 64);
  float* ei            = (float*)alloc(65536 * 4);
  float* ej            = (float*)alloc(65536 * 4);
  float* ra1           = (float*)alloc(128 * 4);
  float* ra2           = (float*)alloc(128 * 4);
  float* rf            = (float*)alloc(4096 * 4);
  float* bqf           = (float*)alloc(256 * 4);
  float* w1            = (float*)alloc(2048 * 4);
  float* w2            = (float*)alloc(2048 * 4);
  float* c1            = (float*)alloc(8 * 4);
  float* c2            = (float*)alloc(8 * 4);
  unsigned short* Bcat = (unsigned short*)alloc((size_t)256 * 512 * 2);
  unsigned short* fcwT = (unsigned short*)alloc((size_t)65536 * 2);
  unsigned short* skwb = (unsigned short*)alloc((size_t)131072 * 2);
  float* sqT           = (float*)alloc((size_t)131072 * 4);
  float* soT           = (float*)alloc((size_t)131072 * 4);
  float* qst           = (float*)alloc(4096 * 4);
  float* atts          = (float*)alloc(4096 * 4);

  hipMemcpyAsync(nodes, data, (size_t)NODES_ELEMS * sizeof(float),
                 hipMemcpyDeviceToDevice, stream);

  // one-time precomputes
  w12_kernel<<<8, 256, 0, stream>>>(WQw, WQb, a1, a2, w1, w2, c1, c2);
  bcat_m1_kernel<<<128, 256, 0, stream>>>(WQw, fcw_g, Bcat);
  bcat_m2_kernel<<<256, 256, 0, stream>>>(fcw_g, Bcat);
  bqf_kernel<<<8, 32, 0, stream>>>(WQb, fcw_g, bqf);
  fcwT_kernel<<<256, 256, 0, stream>>>(fc_w, fcwT);
  cvt_bf16_kernel<<<512, 256, 0, stream>>>(sk_w, skwb, 131072);
  cvt_bf16_kernel<<<8192, 256, 0, stream>>>(data, datab, 8192 * 256);
  edge_pack_kernel<<<2048, 256, 0, stream>>>(edge, ep);
  for (int it = 0; it < 2; it++) {
    transpose_kernel<<<256, 256, 0, stream>>>(sq_w + it * 65536, sqT + it * 65536, 256, 256);
    transpose_kernel<<<256, 256, 0, stream>>>(so_w + it * 65536, soT + it * 65536, 256, 256);
  }
  // relay + extras for it=0 (ra/rf/qst + yb relay rows)
  relay_init_kernel<<<BB, 256, 0, stream>>>(data, a1, a2, fcw_g, fcb_g, bqf,
                                            sqT, sq_b, ra1, ra2, rf, qst, yb, relay);

  for (int it = 0; it < 2; it++) {
    lnei_kernel<<<2048, 256, 0, stream>>>(nodes, data, ng + it * 256, nb + it * 256,
                                          w1, w2, a1, a2, c1, c2, ra1, ra2,
                                          xnb, ei, ej);
    g_gemm_kernel<<<dim3(4, 64), 256, 0, stream>>>(xnb, datab, Bcat, GT);
    gat_agg_kernel<<<NHEAD * BB * 16, 256, 0, stream>>>(GT, ei, ej, ep, rf, tmpb);
    // nodes = mask ? nodes + lrelu(temp @ fc_w + fc_b) : 0  (+ yb bf16 rows)
    mfma_gemm_kernel<<<dim3(4, 64), 256, 0, stream>>>(tmpb, fcwT, fc_b, 8192, 1,
                                                      nodes, nullptr, nodes, mask, yb);
    // ktb = bf16( y @ sk_wT + sk_b )
    mfma_gemm_kernel<<<dim3(4, 65), 256, 0, stream>>>(yb, skwb + it * 65536,
                                                      sk_b + it * 256, 8208, 2,
                                                      nullptr, ktb, nullptr, nullptr, nullptr);
    star_attn_kernel<<<BB * NHEAD, 256, 0, stream>>>(qst, ktb, mask, atts);
    // relay update + extras for next iter
    int nx = (it == 0) ? 1 : 1;   // index for sq of next iter (unused when it==1)
    relay_update_kernel<<<BB, 256, 0, stream>>>(atts, soT + it * 65536, so_b + it * 256,
                                                a1, a2, fcw_g, fcb_g, bqf,
                                                sqT + nx * 65536, sq_b + nx * 256,
                                                (it == 0) ? 1 : 0,
                                                ra1, ra2, rf, qst, yb, relay);
  }
}

// Round 7
// 453.729 us; speedup vs baseline: 1.1019x; 1.1019x over previous
//
#include <hip/hip_runtime.h>
#include <hip/hip_bf16.h>
#include <math.h>

#define BB 16
#define LL 512
#define HH 256
#define NHEAD 8
#define HDIM 32
#define LP1 513
#define NHHD 256
#define NODES_ELEMS (BB*LL*HH)

typedef __attribute__((ext_vector_type(8))) short bf16x8;
typedef __attribute__((ext_vector_type(4))) float f32x4;

__device__ __forceinline__ unsigned short f2bf(float f) {
  union { float f; unsigned u; } x; x.f = f;
  unsigned r = x.u + 0x7fffu + ((x.u >> 16) & 1u);
  return (unsigned short)(r >> 16);
}
__device__ __forceinline__ float bf2f(unsigned short u) {
  union { unsigned u; float f; } x; x.u = (unsigned)u << 16; return x.f;
}

// ---------------------------------------------------------------------------
// fused: nodes = data (fp32) ; datab = bf16(data)
__global__ __launch_bounds__(256) void copy_cvt_kernel(const float* __restrict__ data,
                                                       float* __restrict__ nodes,
                                                       unsigned short* __restrict__ datab) {
  int idx = blockIdx.x * 1024 + threadIdx.x;
#pragma unroll
  for (int u = 0; u < 4; u++) {
    float v = data[idx];
    nodes[idx] = v;
    datab[idx] = f2bf(v);
    idx += 256;
  }
}

__global__ __launch_bounds__(256) void transpose_kernel(const float* __restrict__ in,
                                                        float* __restrict__ out,
                                                        int R, int C) {
  int idx = blockIdx.x * 256 + threadIdx.x;
  if (idx < R * C) {
    int r = idx / C, c = idx % C;
    out[(size_t)c * R + r] = in[idx];
  }
}

__global__ __launch_bounds__(256) void cvt_bf16_kernel(const float* __restrict__ in,
                                                       unsigned short* __restrict__ out,
                                                       int n) {
  int idx = blockIdx.x * 256 + threadIdx.x;
  if (idx < n) out[idx] = f2bf(in[idx]);
}

// edge -> packed bits
__global__ __launch_bounds__(256) void edge_pack_kernel(const int* __restrict__ edge,
                                                        unsigned char* __restrict__ ep) {
  int row = blockIdx.x * 4 + (threadIdx.x >> 6);
  int lane = threadIdx.x & 63;
  const int* adj = edge + ((size_t)row << 9);
  unsigned v = 0;
#pragma unroll
  for (int u = 0; u < 8; u++) v |= (adj[lane + 64 * u] > 0 ? 1u : 0u) << u;
  ep[((size_t)row << 6) + lane] = (unsigned char)v;
}

// fc_w [256 k][256 o] -> fcwT[o][k] bf16
__global__ __launch_bounds__(256) void fcwT_kernel(const float* __restrict__ in,
                                                   unsigned short* __restrict__ out) {
  int idx = blockIdx.x * 256 + threadIdx.x;
  int o = idx >> 8, k = idx & 255;
  out[idx] = f2bf(in[k * 256 + o]);
}

// Bcat M1: Bcat[(n*32+d)*512 + k] = sum_c WQw[n][c][k] * Fw[n][c][d]
__global__ __launch_bounds__(256) void bcat_m1_kernel(const float* __restrict__ WQw,
                                                      const float* __restrict__ fcw,
                                                      unsigned short* __restrict__ Bcat) {
  __shared__ float wq_s[256][16];
  __shared__ float fw_s[256][32];
  int n = blockIdx.x >> 4, kt = blockIdx.x & 15;
  int t = threadIdx.x;
#pragma unroll
  for (int i = 0; i < 16; i++) {
    int c = i * 16 + (t >> 4), kk = t & 15;
    wq_s[c][kk] = WQw[(size_t)n * 65536 + c * 256 + kt * 16 + kk];
  }
#pragma unroll
  for (int i = 0; i < 32; i++) {
    int idx = i * 256 + t;
    fw_s[idx >> 5][idx & 31] = fcw[(size_t)n * 24576 + idx];
  }
  __syncthreads();
  int kloc = t >> 4, dp = t & 15;
  float a0 = 0.f, a1v = 0.f;
  for (int c = 0; c < 256; c++) {
    float wv = wq_s[c][kloc];
    a0 = fmaf(wv, fw_s[c][dp * 2], a0);
    a1v = fmaf(wv, fw_s[c][dp * 2 + 1], a1v);
  }
  int k = kt * 16 + kloc;
  Bcat[((size_t)n * 32 + dp * 2) * 512 + k] = f2bf(a0);
  Bcat[((size_t)n * 32 + dp * 2 + 1) * 512 + k] = f2bf(a1v);
}

// Bcat data half
__global__ __launch_bounds__(256) void bcat_m2_kernel(const float* __restrict__ fcw,
                                                      unsigned short* __restrict__ Bcat) {
  int idx = blockIdx.x * 256 + threadIdx.x;
  int n = idx >> 13, d = (idx >> 8) & 31, c = idx & 255;
  Bcat[((size_t)n * 32 + d) * 512 + 256 + c] =
      f2bf(fcw[((size_t)n * 768 + 256 + 2 * c) * 32 + d]);
}

// bqf[n][d] = sum_c WQb[n][c] * Fw[n][c][d]
__global__ __launch_bounds__(32) void bqf_kernel(const float* __restrict__ WQb,
                                                 const float* __restrict__ fcw,
                                                 float* __restrict__ bqf) {
  int n = blockIdx.x, d = threadIdx.x;
  float s = 0.f;
  for (int c = 0; c < 256; c++)
    s = fmaf(WQb[n * 256 + c], fcw[((size_t)n * 768 + c) * 32 + d], s);
  bqf[n * 32 + d] = s;
}

// w1/w2/c1/c2 folded attention weights
__global__ __launch_bounds__(256) void w12_kernel(const float* __restrict__ WQw,
                                                  const float* __restrict__ WQb,
                                                  const float* __restrict__ a1,
                                                  const float* __restrict__ a2,
                                                  float* __restrict__ w1,
                                                  float* __restrict__ w2,
                                                  float* __restrict__ c1,
                                                  float* __restrict__ c2) {
  int n = blockIdx.x, t = threadIdx.x;
  float s1 = 0.f, s2 = 0.f;
  for (int c = 0; c < 256; c++) {
    float wv = WQw[((size_t)(n * 256 + c)) * 256 + t];
    s1 = fmaf(a1[n * 768 + c], wv, s1);
    s2 = fmaf(a2[n * 768 + c], wv, s2);
  }
  w1[n * 256 + t] = s1;
  w2[n * 256 + t] = s2;
  __shared__ float r1[256], r2[256];
  r1[t] = a1[n * 768 + t] * WQb[n * 256 + t];
  r2[t] = a2[n * 768 + t] * WQb[n * 256 + t];
  __syncthreads();
  for (int o = 128; o; o >>= 1) {
    if (t < o) { r1[t] += r1[t + o]; r2[t] += r2[t + o]; }
    __syncthreads();
  }
  if (t == 0) { c1[n] = r1[0]; c2[n] = r2[0]; }
}

// ---------------------------------------------------------------------------
// relay mean, phase 1: partial[b*8+chunk][256] over 64 rows
__global__ __launch_bounds__(256) void relay_part_kernel(const float* __restrict__ data,
                                                         float* __restrict__ part) {
  int b = blockIdx.x >> 3, ch = blockIdx.x & 7;
  int t = threadIdx.x;
  float s = 0.f;
  const float* p = data + ((size_t)b * 512 + ch * 64) * 256 + t;
  for (int l = 0; l < 64; l++) s += p[(size_t)l * 256];
  part[(size_t)blockIdx.x * 256 + t] = s;
}

// relay mean, phase 2: relay fp32 + yb bf16 relay row
__global__ __launch_bounds__(256) void relay_fin_kernel(const float* __restrict__ part,
                                                        float* __restrict__ relay,
                                                        unsigned short* __restrict__ yb) {
  int b = blockIdx.x, t = threadIdx.x;
  float s = 0.f;
#pragma unroll
  for (int ch = 0; ch < 8; ch++) s += part[((size_t)(b * 8 + ch)) * 256 + t];
  s *= (1.0f / 512.0f);
  relay[b * 256 + t] = s;
  yb[((size_t)b * LP1) * 256 + t] = f2bf(s);
}

// rarf: ra1/ra2 + rf(+fcb+bqf)
__global__ __launch_bounds__(256) void rarf_kernel(const float* __restrict__ relay,
                                                   const float* __restrict__ a1,
                                                   const float* __restrict__ a2,
                                                   const float* __restrict__ fcw,
                                                   const float* __restrict__ fcb,
                                                   const float* __restrict__ bqf,
                                                   float* __restrict__ ra1,
                                                   float* __restrict__ ra2,
                                                   float* __restrict__ rf) {
  int n = blockIdx.x >> 4, b = blockIdx.x & 15;
  int t = threadIdx.x;
  int lane = t & 63, w = t >> 6;
  __shared__ float rel[256];
  __shared__ float red1[4], red2[4];
  __shared__ float pf_s[8][33];
  rel[t] = relay[b * HH + t];
  __syncthreads();
  float p1 = rel[t] * a1[n * 768 + 257 + 2 * t];
  float p2 = rel[t] * a2[n * 768 + 257 + 2 * t];
#pragma unroll
  for (int o = 32; o; o >>= 1) { p1 += __shfl_xor(p1, o); p2 += __shfl_xor(p2, o); }
  if (lane == 0) { red1[w] = p1; red2[w] = p2; }
  int d = t & 31, seg = t >> 5;
  float pf = 0.f;
  for (int u = 0; u < 32; u++) {
    int k = seg * 32 + u;
    pf = fmaf(rel[k], fcw[((size_t)n * 768 + 257 + 2 * k) * 32 + d], pf);
  }
  pf_s[seg][d] = pf;
  __syncthreads();
  if (t == 0) {
    ra1[n * 16 + b] = red1[0] + red1[1] + red1[2] + red1[3];
    ra2[n * 16 + b] = red2[0] + red2[1] + red2[2] + red2[3];
  }
  if (t < 32) {
    float s = 0.f;
    for (int gg = 0; gg < 8; gg++) s += pf_s[gg][t];
    rf[((size_t)n * 16 + b) * 32 + t] = s + fcb[n * 32 + t] + bqf[n * 32 + t];
  }
}

// ---------------------------------------------------------------------------
// Fused LayerNorm + ei/ej
__global__ __launch_bounds__(256) void lnei_kernel(const float* __restrict__ nodes,
                                                   const float* __restrict__ data,
                                                   const float* __restrict__ g,
                                                   const float* __restrict__ bb,
                                                   const float* __restrict__ w1,
                                                   const float* __restrict__ w2,
                                                   const float* __restrict__ a1,
                                                   const float* __restrict__ a2,
                                                   const float* __restrict__ c1,
                                                   const float* __restrict__ c2,
                                                   const float* __restrict__ ra1,
                                                   const float* __restrict__ ra2,
                                                   unsigned short* __restrict__ xnb,
                                                   float* __restrict__ ei,
                                                   float* __restrict__ ej) {
  int r = blockIdx.x * 4 + (threadIdx.x >> 6);
  int b = r >> 9;
  int lane = threadIdx.x & 63;
  float x[4], dv[4];
#pragma unroll
  for (int u = 0; u < 4; u++) {
    int c = lane + 64 * u;
    x[u] = nodes[(size_t)r * 256 + c];
    dv[u] = data[(size_t)r * 256 + c];
  }
  float s = x[0] + x[1] + x[2] + x[3];
#pragma unroll
  for (int o = 32; o; o >>= 1) s += __shfl_xor(s, o);
  float mean = s * (1.0f / 256.0f);
  float v = 0.f;
#pragma unroll
  for (int u = 0; u < 4; u++) { x[u] -= mean; v = fmaf(x[u], x[u], v); }
#pragma unroll
  for (int o = 32; o; o >>= 1) v += __shfl_xor(v, o);
  float rstd = rsqrtf(v * (1.0f / 256.0f) + 1e-5f);
  float xv[4];
#pragma unroll
  for (int u = 0; u < 4; u++) {
    int c = lane + 64 * u;
    xv[u] = x[u] * rstd * g[c] + bb[c];
    xnb[(size_t)r * 256 + c] = f2bf(xv[u]);
  }
  for (int n = 0; n < 8; n++) {
    float s1 = 0.f, s2 = 0.f;
#pragma unroll
    for (int u = 0; u < 4; u++) {
      int c = lane + 64 * u;
      s1 = fmaf(xv[u], w1[n * 256 + c], s1);
      s1 = fmaf(dv[u], a1[n * 768 + 256 + 2 * c], s1);
      s2 = fmaf(xv[u], w2[n * 256 + c], s2);
      s2 = fmaf(dv[u], a2[n * 768 + 256 + 2 * c], s2);
    }
#pragma unroll
    for (int o = 32; o; o >>= 1) { s1 += __shfl_xor(s1, o); s2 += __shfl_xor(s2, o); }
    if (lane == 0) {
      ei[n * 8192 + r] = s1 + c1[n] + ra1[n * 16 + b];
      ej[n * 8192 + r] = s2 + c2[n] + ra2[n * 16 + b];
    }
  }
}

// ---------------------------------------------------------------------------
// G-GEMM: GT[n][b][d][j] = [xn ; data](row j) @ Bcat col (n*32+d)
__global__ __launch_bounds__(256) void g_gemm_kernel(
    const unsigned short* __restrict__ A1, const unsigned short* __restrict__ A2,
    const unsigned short* __restrict__ Bcat, unsigned short* __restrict__ GT) {
  int tileN = blockIdx.x * 64;
  int tileM = blockIdx.y * 128;
  int t = threadIdx.x;
  int wv = t >> 6, lane = t & 63;
  int lo = lane & 15, quad = lane >> 4;
  int rowBase0 = tileM + wv * 32;
  const unsigned short* ap1[2];
  const unsigned short* ap2[2];
#pragma unroll
  for (int rt = 0; rt < 2; rt++) {
    int arow = rowBase0 + rt * 16 + lo;
    ap1[rt] = A1 + (size_t)arow * 256 + quad * 8;
    ap2[rt] = A2 + (size_t)arow * 256 + quad * 8;
  }
  f32x4 acc[2][4] = {};
  for (int k0 = 0; k0 < 512; k0 += 32) {
    bf16x8 af[2];
#pragma unroll
    for (int rt = 0; rt < 2; rt++)
      af[rt] = (k0 < 256) ? *(const bf16x8*)(ap1[rt] + k0)
                          : *(const bf16x8*)(ap2[rt] + k0 - 256);
#pragma unroll
    for (int ct = 0; ct < 4; ct++) {
      bf16x8 bf_ = *(const bf16x8*)(Bcat + (size_t)(tileN + ct * 16 + lo) * 512 + k0 + quad * 8);
#pragma unroll
      for (int rt = 0; rt < 2; rt++)
        acc[rt][ct] = __builtin_amdgcn_mfma_f32_16x16x32_bf16(af[rt], bf_, acc[rt][ct], 0, 0, 0);
    }
  }
#pragma unroll
  for (int rt = 0; rt < 2; rt++) {
#pragma unroll
    for (int ct = 0; ct < 4; ct++) {
      int co = tileN + ct * 16 + lo;
      int n = co >> 5, d = co & 31;
      int jrow = rowBase0 + rt * 16 + quad * 4;
      int b2 = jrow >> 9, jj = jrow & 511;
      ushort4 pk;
      pk.x = f2bf(acc[rt][ct][0]);
      pk.y = f2bf(acc[rt][ct][1]);
      pk.z = f2bf(acc[rt][ct][2]);
      pk.w = f2bf(acc[rt][ct][3]);
      *(ushort4*)&GT[(((size_t)(n * 16 + b2) * 32 + d) << 9) + jj] = pk;
    }
  }
}

// ---------------------------------------------------------------------------
// MFMA GEMM K=256: mode 1 fc epilogue (nodes fp32 + yb bf16); mode 2 bf16 out
__global__ __launch_bounds__(256) void mfma_gemm_kernel(
    const unsigned short* __restrict__ A, const unsigned short* __restrict__ Bw,
    const float* __restrict__ bias, int Mvalid, int mode,
    float* __restrict__ outF, unsigned short* __restrict__ outB,
    const float* __restrict__ resid, const int* __restrict__ mask,
    unsigned short* __restrict__ yb) {
  int tileN = blockIdx.x * 64;
  int tileM = blockIdx.y * 128;
  int t = threadIdx.x;
  int wv = t >> 6, lane = t & 63;
  int lo = lane & 15, quad = lane >> 4;
  int rowBase0 = tileM + wv * 32;
  const unsigned short* aptr[2];
#pragma unroll
  for (int rt = 0; rt < 2; rt++) {
    int arow = rowBase0 + rt * 16 + lo;
    if (arow >= Mvalid) arow = Mvalid - 1;
    aptr[rt] = A + (size_t)arow * 256 + quad * 8;
  }
  f32x4 acc[2][4] = {};
  for (int k0 = 0; k0 < 256; k0 += 32) {
    bf16x8 af[2];
#pragma unroll
    for (int rt = 0; rt < 2; rt++) af[rt] = *(const bf16x8*)(aptr[rt] + k0);
#pragma unroll
    for (int ct = 0; ct < 4; ct++) {
      bf16x8 bf_ = *(const bf16x8*)(Bw + (size_t)(tileN + ct * 16 + lo) * 256 + k0 + quad * 8);
#pragma unroll
      for (int rt = 0; rt < 2; rt++)
        acc[rt][ct] = __builtin_amdgcn_mfma_f32_16x16x32_bf16(af[rt], bf_, acc[rt][ct], 0, 0, 0);
    }
  }
#pragma unroll
  for (int rt = 0; rt < 2; rt++) {
    int rowBase = rowBase0 + rt * 16;
#pragma unroll
    for (int ct = 0; ct < 4; ct++) {
      int co = tileN + ct * 16 + lo;
      float bv = bias[co];
#pragma unroll
      for (int r = 0; r < 4; r++) {
        int row = rowBase + quad * 4 + r;
        if (row >= Mvalid) continue;
        float v = acc[rt][ct][r] + bv;
        if (mode == 1) {
          v = v > 0.f ? v : 0.01f * v;
          v = (mask[row] != 0) ? resid[(size_t)row * 256 + co] + v : 0.f;
          outF[(size_t)row * 256 + co] = v;
          yb[((size_t)(row + (row >> 9) + 1)) * 256 + co] = f2bf(v);
        } else {
          outB[(size_t)row * 256 + co] = f2bf(v);
        }
      }
    }
  }
}

// ---------------------------------------------------------------------------
// GAT: softmax (packed-edge) -> tiny MFMA aggregation vs pre-projected GT
__global__ __launch_bounds__(256) void gat_agg_kernel(
    const unsigned short* __restrict__ GT,
    const float* __restrict__ ei, const float* __restrict__ ej,
    const unsigned char* __restrict__ ep,
    const float* __restrict__ rf,
    unsigned short* __restrict__ tempb) {
  __shared__ unsigned short W[32][512];
  int blk = blockIdx.x;
  int n = blk >> 8;
  int b = (blk >> 4) & 15;
  int i0 = (blk & 15) << 5;
  int t = threadIdx.x;
  int wv = t >> 6, lane = t & 63;
  int lo = lane & 15, quad = lane >> 4;

  const float* ejrow = ej + n * 8192 + b * 512;
  float ejv[8];
#pragma unroll
  for (int u = 0; u < 8; u++) ejv[u] = ejrow[lane + 64 * u];
  for (int rr = 0; rr < 8; rr++) {
    int row = wv * 8 + rr;
    float eiv = ei[n * 8192 + b * 512 + i0 + row];
    unsigned pb = ep[(((size_t)(b * 512 + i0 + row)) << 6) + lane];
    float evv[8];
    float m = -3.0e38f;
#pragma unroll
    for (int u = 0; u < 8; u++) {
      float e;
      if ((pb >> u) & 1) { e = eiv + ejv[u]; e = e > 0.f ? e : 0.2f * e; }
      else e = -9.0e15f;
      evv[u] = e;
      m = fmaxf(m, e);
    }
#pragma unroll
    for (int o = 32; o; o >>= 1) m = fmaxf(m, __shfl_xor(m, o));
    float s = 0.f;
#pragma unroll
    for (int u = 0; u < 8; u++) {
      float wexp = __expf(evv[u] - m);
      evv[u] = wexp;
      s += wexp;
    }
#pragma unroll
    for (int o = 32; o; o >>= 1) s += __shfl_xor(s, o);
    float inv = 1.0f / s;
    int rx = (row & 7) << 3;
#pragma unroll
    for (int u = 0; u < 8; u++) {
      int col = lane + 64 * u;
      W[row][((col >> 3 << 3) ^ rx) + (col & 7)] = f2bf(evv[u] * inv);
    }
  }
  __syncthreads();

  int rt = wv >> 1, dh = wv & 1;
  int arow = rt * 16 + lo;
  int rx = arow & 7;
  const unsigned short* gtb = GT + (((size_t)(n * 16 + b) * 32) << 9);
  f32x4 acc = {};
  for (int k0 = 0; k0 < 512; k0 += 32) {
    int chunk = (k0 >> 3) + quad;
    bf16x8 a0 = *(const bf16x8*)&W[arow][(chunk ^ rx) << 3];
    bf16x8 bf_ = *(const bf16x8*)(gtb + (((size_t)(dh * 16 + lo)) << 9) + k0 + quad * 8);
    acc = __builtin_amdgcn_mfma_f32_16x16x32_bf16(a0, bf_, acc, 0, 0, 0);
  }
  int d = dh * 16 + lo;
  float base = rf[((size_t)n * 16 + b) * 32 + d];
#pragma unroll
  for (int r = 0; r < 4; r++) {
    int row = rt * 16 + quad * 4 + r;
    float v = acc[r] + base;
    v = v > 0.f ? v : expm1f(v);
    tempb[((size_t)(b * 512 + i0 + row)) * 256 + n * 32 + d] = f2bf(v);
  }
}

// ---------------------------------------------------------------------------
// star attention on bf16 kt, q computed in-block from relay
__global__ __launch_bounds__(256) void star_attn_kernel(const float* __restrict__ relay,
                                                        const float* __restrict__ sqT_it,
                                                        const float* __restrict__ sqb_it,
                                                        const unsigned short* __restrict__ ktb,
                                                        const int* __restrict__ mask,
                                                        float* __restrict__ attstar) {
  int b = blockIdx.x >> 3, n = blockIdx.x & 7;
  int t = threadIdx.x;
  int lane = t & 63, w = t >> 6;
  __shared__ float relb[256];
  __shared__ float qv[32];
  __shared__ float pre[LP1];
  __shared__ float red[4];
  __shared__ float par[8][33];
  relb[t] = relay[b * 256 + t];
  __syncthreads();
  {
    int d = t & 31, g = t >> 5;
    float qp = 0.f;
    for (int k = 0; k < 32; k++)
      qp = fmaf(relb[g * 32 + k], sqT_it[(size_t)(g * 32 + k) * 256 + n * 32 + d], qp);
    par[g][d] = qp;
  }
  __syncthreads();
  if (t < 32) {
    float q = 0.f;
#pragma unroll
    for (int gg = 0; gg < 8; gg++) q += par[gg][t];
    qv[t] = q + sqb_it[n * 32 + t];
  }
  __syncthreads();
  const float scale = 0.17677669529663687f;
  for (int l = t; l < LP1; l += 256) {
    bool masked = (l > 0) && (mask[b * LL + l - 1] == 0);
    float p;
    if (masked) p = -3.4e38f;
    else {
      p = 0.f;
      const unsigned short* krow = ktb + ((size_t)b * LP1 + l) * 256 + n * 32;
#pragma unroll
      for (int d = 0; d < 32; d++) p = fmaf(qv[d], bf2f(krow[d]), p);
      p *= scale;
    }
    pre[l] = p;
  }
  __syncthreads();
  float m = -3.4e38f;
  for (int l = t; l < LP1; l += 256) m = fmaxf(m, pre[l]);
#pragma unroll
  for (int o = 32; o; o >>= 1) m = fmaxf(m, __shfl_xor(m, o));
  if (lane == 0) red[w] = m;
  __syncthreads();
  m = fmaxf(fmaxf(red[0], red[1]), fmaxf(red[2], red[3]));
  __syncthreads();
  float s = 0.f;
  for (int l = t; l < LP1; l += 256) {
    float wv = __expf(pre[l] - m);
    pre[l] = wv;
    s += wv;
  }
#pragma unroll
  for (int o = 32; o; o >>= 1) s += __shfl_xor(s, o);
  if (lane == 0) red[w] = s;
  __syncthreads();
  float denom = red[0] + red[1] + red[2] + red[3];
  int d = t & 31, g = t >> 5;
  float acc = 0.f;
  for (int l = g; l < LP1; l += 8)
    acc = fmaf(pre[l], bf2f(ktb[((size_t)b * LP1 + l) * 256 + n * 32 + d]), acc);
  par[g][d] = acc;
  __syncthreads();
  if (t < 32) {
    float a = 0.f;
    for (int gg = 0; gg < 8; gg++) a += par[gg][t];
    attstar[b * 256 + n * 32 + t] = a / denom;
  }
}

// ---------------------------------------------------------------------------
// relay = lrelu(atts @ soT + sob); writes relay fp32 + yb bf16 relay row
__global__ __launch_bounds__(256) void so_update_kernel(const float* __restrict__ atts,
                                                        const float* __restrict__ soT_it,
                                                        const float* __restrict__ sob_it,
                                                        float* __restrict__ relay,
                                                        unsigned short* __restrict__ yb) {
  int b = blockIdx.x, t = threadIdx.x;
  __shared__ float xr[256];
  xr[t] = atts[b * 256 + t];
  __syncthreads();
  float acc = 0.f;
  for (int k = 0; k < 256; k++) acc = fmaf(xr[k], soT_it[(size_t)k * 256 + t], acc);
  float v = acc + sob_it[t];
  v = v > 0.f ? v : 0.01f * v;
  relay[b * 256 + t] = v;
  yb[((size_t)b * LP1) * 256 + t] = f2bf(v);
}

// ---------------------------------------------------------------------------
extern "C" void kernel_launch(void* const* d_in, const int* in_sizes, int n_in,
                              void* d_out, int out_size, void* d_ws, size_t ws_size,
                              hipStream_t stream) {
  const float* data  = (const float*)d_in[0];
  const float* WQw   = (const float*)d_in[1];
  const float* WQb   = (const float*)d_in[2];
  const float* a1    = (const float*)d_in[3];
  const float* a2    = (const float*)d_in[4];
  const float* fcw_g = (const float*)d_in[5];
  const float* fcb_g = (const float*)d_in[6];
  const float* ng    = (const float*)d_in[7];
  const float* nb    = (const float*)d_in[8];
  const float* sq_w  = (const float*)d_in[9];
  const float* sq_b  = (const float*)d_in[10];
  const float* sk_w  = (const float*)d_in[11];
  const float* sk_b  = (const float*)d_in[12];
  const float* so_w  = (const float*)d_in[13];
  const float* so_b  = (const float*)d_in[14];
  const float* fc_w  = (const float*)d_in[15];
  const float* fc_b  = (const float*)d_in[16];
  const int*   mask  = (const int*)d_in[17];
  const int*   edge  = (const int*)d_in[18];

  float* nodes = (float*)d_out;
  float* relay = nodes + NODES_ELEMS;

  char* p = (char*)d_ws;
  auto alloc = [&](size_t bytes) -> char* {
    char* r = p; p += (bytes + 255) & ~(size_t)255; return r;
  };
  unsigned short* xnb  = (unsigned short*)alloc((size_t)8192 * 256 * 2);
  unsigned short* datab= (unsigned short*)alloc((size_t)8192 * 256 * 2);
  unsigned short* GT   = (unsigned short*)alloc((size_t)8 * 16 * 32 * 512 * 2);
  unsigned short* tmpb = (unsigned short*)alloc((size_t)8192 * 256 * 2);
  unsigned short* yb   = (unsigned short*)alloc((size_t)8208 * 256 * 2);
  unsigned short* ktb  = (unsigned short*)alloc((size_t)8208 * 256 * 2);
  unsigned char* ep    = (unsigned char*)alloc((size_t)8192 * 64);
  float* ei            = (float*)alloc(65536 * 4);
  float* ej            = (float*)alloc(65536 * 4);
  float* ra1           = (float*)alloc(128 * 4);
  float* ra2           = (float*)alloc(128 * 4);
  float* rf            = (float*)alloc(4096 * 4);
  float* bqf           = (float*)alloc(256 * 4);
  float* w1            = (float*)alloc(2048 * 4);
  float* w2            = (float*)alloc(2048 * 4);
  float* c1            = (float*)alloc(8 * 4);
  float* c2            = (float*)alloc(8 * 4);
  float* rpart         = (float*)alloc(128 * 256 * 4);
  unsigned short* Bcat = (unsigned short*)alloc((size_t)256 * 512 * 2);
  unsigned short* fcwT = (unsigned short*)alloc((size_t)65536 * 2);
  unsigned short* skwb = (unsigned short*)alloc((size_t)131072 * 2);
  float* sqT           = (float*)alloc((size_t)131072 * 4);
  float* soT           = (float*)alloc((size_t)131072 * 4);
  float* atts          = (float*)alloc(4096 * 4);

  // one-time precomputes
  copy_cvt_kernel<<<2048, 256, 0, stream>>>(data, nodes, datab);
  w12_kernel<<<8, 256, 0, stream>>>(WQw, WQb, a1, a2, w1, w2, c1, c2);
  bcat_m1_kernel<<<128, 256, 0, stream>>>(WQw, fcw_g, Bcat);
  bcat_m2_kernel<<<256, 256, 0, stream>>>(fcw_g, Bcat);
  bqf_kernel<<<8, 32, 0, stream>>>(WQb, fcw_g, bqf);
  fcwT_kernel<<<256, 256, 0, stream>>>(fc_w, fcwT);
  cvt_bf16_kernel<<<512, 256, 0, stream>>>(sk_w, skwb, 131072);
  edge_pack_kernel<<<2048, 256, 0, stream>>>(edge, ep);
  for (int it = 0; it < 2; it++) {
    transpose_kernel<<<256, 256, 0, stream>>>(sq_w + it * 65536, sqT + it * 65536, 256, 256);
    transpose_kernel<<<256, 256, 0, stream>>>(so_w + it * 65536, soT + it * 65536, 256, 256);
  }
  relay_part_kernel<<<128, 256, 0, stream>>>(data, rpart);
  relay_fin_kernel<<<BB, 256, 0, stream>>>(rpart, relay, yb);

  for (int it = 0; it < 2; it++) {
    rarf_kernel<<<NHEAD * BB, 256, 0, stream>>>(relay, a1, a2, fcw_g, fcb_g, bqf,
                                                ra1, ra2, rf);
    lnei_kernel<<<2048, 256, 0, stream>>>(nodes, data, ng + it * 256, nb + it * 256,
                                          w1, w2, a1, a2, c1, c2, ra1, ra2,
                                          xnb, ei, ej);
    g_gemm_kernel<<<dim3(4, 64), 256, 0, stream>>>(xnb, datab, Bcat, GT);
    gat_agg_kernel<<<NHEAD * BB * 16, 256, 0, stream>>>(GT, ei, ej, ep, rf, tmpb);
    // nodes = mask ? nodes + lrelu(temp @ fc_w + fc_b) : 0  (+ yb bf16 rows)
    mfma_gemm_kernel<<<dim3(4, 64), 256, 0, stream>>>(tmpb, fcwT, fc_b, 8192, 1,
                                                      nodes, nullptr, nodes, mask, yb);
    // ktb = bf16( y @ sk_wT + sk_b )
    mfma_gemm_kernel<<<dim3(4, 65), 256, 0, stream>>>(yb, skwb + it * 65536,
                                                      sk_b + it * 256, 8208, 2,
                                                      nullptr, ktb, nullptr, nullptr, nullptr);
    star_attn_kernel<<<BB * NHEAD, 256, 0, stream>>>(relay, sqT + it * 65536,
                                                     sq_b + it * 256, ktb, mask, atts);
    so_update_kernel<<<BB, 256, 0, stream>>>(atts, soT + it * 65536, so_b + it * 256,
                                             relay, yb);
  }
}

// Round 8
// 436.452 us; speedup vs baseline: 1.1455x; 1.0396x over previous
//
#include <hip/hip_runtime.h>
#include <hip/hip_bf16.h>
#include <math.h>

#define BB 16
#define LL 512
#define HH 256
#define NHEAD 8
#define HDIM 32
#define LP1 513
#define NHHD 256
#define NODES_ELEMS (BB*LL*HH)

typedef __attribute__((ext_vector_type(8))) short bf16x8;
typedef __attribute__((ext_vector_type(4))) float f32x4;

__device__ __forceinline__ unsigned short f2bf(float f) {
  union { float f; unsigned u; } x; x.f = f;
  unsigned r = x.u + 0x7fffu + ((x.u >> 16) & 1u);
  return (unsigned short)(r >> 16);
}
__device__ __forceinline__ float bf2f(unsigned short u) {
  union { unsigned u; float f; } x; x.u = (unsigned)u << 16; return x.f;
}

// ---------------------------------------------------------------------------
// fused: nodes = data (fp32) ; datab = bf16(data)
__global__ __launch_bounds__(256) void copy_cvt_kernel(const float* __restrict__ data,
                                                       float* __restrict__ nodes,
                                                       unsigned short* __restrict__ datab) {
  int idx = blockIdx.x * 1024 + threadIdx.x;
#pragma unroll
  for (int u = 0; u < 4; u++) {
    float v = data[idx];
    nodes[idx] = v;
    datab[idx] = f2bf(v);
    idx += 256;
  }
}

// 4 weight transposes in one launch: y = {sq0, sq1, so0, so1}
__global__ __launch_bounds__(256) void transpose4_kernel(const float* __restrict__ sq_w,
                                                         const float* __restrict__ so_w,
                                                         float* __restrict__ sqT,
                                                         float* __restrict__ soT) {
  int which = blockIdx.y;
  const float* in = (which < 2) ? sq_w + which * 65536 : so_w + (which - 2) * 65536;
  float* out = (which < 2) ? sqT + which * 65536 : soT + (which - 2) * 65536;
  int idx = blockIdx.x * 256 + threadIdx.x;
  int r = idx >> 8, c = idx & 255;
  out[c * 256 + r] = in[idx];
}

// merged elementwise preps: fcwT (256 blk) | bcat_m2 (256 blk) | sk cvt (512 blk)
__global__ __launch_bounds__(256) void prep_misc_kernel(const float* __restrict__ fc_w,
                                                        const float* __restrict__ fcw,
                                                        const float* __restrict__ sk_w,
                                                        unsigned short* __restrict__ fcwT,
                                                        unsigned short* __restrict__ Bcat,
                                                        unsigned short* __restrict__ skwb) {
  int blk = blockIdx.x;
  int t = threadIdx.x;
  if (blk < 256) {
    int idx = blk * 256 + t;           // o*256 + k
    int o = idx >> 8, k = idx & 255;
    fcwT[idx] = f2bf(fc_w[k * 256 + o]);
  } else if (blk < 512) {
    int idx = (blk - 256) * 256 + t;   // n*8192 + d*256 + c
    int n = idx >> 13, d = (idx >> 8) & 31, c = idx & 255;
    Bcat[((size_t)n * 32 + d) * 512 + 256 + c] =
        f2bf(fcw[((size_t)n * 768 + 256 + 2 * c) * 32 + d]);
  } else {
    int idx = (blk - 512) * 256 + t;
    skwb[idx] = f2bf(sk_w[idx]);
  }
}

// edge -> packed bits
__global__ __launch_bounds__(256) void edge_pack_kernel(const int* __restrict__ edge,
                                                        unsigned char* __restrict__ ep) {
  int row = blockIdx.x * 4 + (threadIdx.x >> 6);
  int lane = threadIdx.x & 63;
  const int* adj = edge + ((size_t)row << 9);
  unsigned v = 0;
#pragma unroll
  for (int u = 0; u < 8; u++) v |= (adj[lane + 64 * u] > 0 ? 1u : 0u) << u;
  ep[((size_t)row << 6) + lane] = (unsigned char)v;
}

// Bcat M1: Bcat[(n*32+d)*512 + k] = sum_c WQw[n][c][k] * Fw[n][c][d]
__global__ __launch_bounds__(256) void bcat_m1_kernel(const float* __restrict__ WQw,
                                                      const float* __restrict__ fcw,
                                                      unsigned short* __restrict__ Bcat) {
  __shared__ float wq_s[256][16];
  __shared__ float fw_s[256][32];
  int n = blockIdx.x >> 4, kt = blockIdx.x & 15;
  int t = threadIdx.x;
#pragma unroll
  for (int i = 0; i < 16; i++) {
    int c = i * 16 + (t >> 4), kk = t & 15;
    wq_s[c][kk] = WQw[(size_t)n * 65536 + c * 256 + kt * 16 + kk];
  }
#pragma unroll
  for (int i = 0; i < 32; i++) {
    int idx = i * 256 + t;
    fw_s[idx >> 5][idx & 31] = fcw[(size_t)n * 24576 + idx];
  }
  __syncthreads();
  int kloc = t >> 4, dp = t & 15;
  float a0 = 0.f, a1v = 0.f;
  for (int c = 0; c < 256; c++) {
    float wv = wq_s[c][kloc];
    a0 = fmaf(wv, fw_s[c][dp * 2], a0);
    a1v = fmaf(wv, fw_s[c][dp * 2 + 1], a1v);
  }
  int k = kt * 16 + kloc;
  Bcat[((size_t)n * 32 + dp * 2) * 512 + k] = f2bf(a0);
  Bcat[((size_t)n * 32 + dp * 2 + 1) * 512 + k] = f2bf(a1v);
}

// w1/w2/c1/c2 folded attention weights + bqf, one block per head
__global__ __launch_bounds__(256) void w12bqf_kernel(const float* __restrict__ WQw,
                                                     const float* __restrict__ WQb,
                                                     const float* __restrict__ a1,
                                                     const float* __restrict__ a2,
                                                     const float* __restrict__ fcw,
                                                     float* __restrict__ w1,
                                                     float* __restrict__ w2,
                                                     float* __restrict__ c1,
                                                     float* __restrict__ c2,
                                                     float* __restrict__ bqf) {
  int n = blockIdx.x, t = threadIdx.x;
  float s1 = 0.f, s2 = 0.f;
  for (int c = 0; c < 256; c++) {
    float wv = WQw[((size_t)(n * 256 + c)) * 256 + t];
    s1 = fmaf(a1[n * 768 + c], wv, s1);
    s2 = fmaf(a2[n * 768 + c], wv, s2);
  }
  w1[n * 256 + t] = s1;
  w2[n * 256 + t] = s2;
  if (t < 32) {
    float s = 0.f;
    for (int c = 0; c < 256; c++)
      s = fmaf(WQb[n * 256 + c], fcw[((size_t)n * 768 + c) * 32 + t], s);
    bqf[n * 32 + t] = s;
  }
  __shared__ float r1[256], r2[256];
  r1[t] = a1[n * 768 + t] * WQb[n * 256 + t];
  r2[t] = a2[n * 768 + t] * WQb[n * 256 + t];
  __syncthreads();
  for (int o = 128; o; o >>= 1) {
    if (t < o) { r1[t] += r1[t + o]; r2[t] += r2[t + o]; }
    __syncthreads();
  }
  if (t == 0) { c1[n] = r1[0]; c2[n] = r2[0]; }
}

// ---------------------------------------------------------------------------
// relay mean, phase 1
__global__ __launch_bounds__(256) void relay_part_kernel(const float* __restrict__ data,
                                                         float* __restrict__ part) {
  int b = blockIdx.x >> 3, ch = blockIdx.x & 7;
  int t = threadIdx.x;
  float s = 0.f;
  const float* p = data + ((size_t)b * 512 + ch * 64) * 256 + t;
  for (int l = 0; l < 64; l++) s += p[(size_t)l * 256];
  part[(size_t)blockIdx.x * 256 + t] = s;
}

// relay mean, phase 2
__global__ __launch_bounds__(256) void relay_fin_kernel(const float* __restrict__ part,
                                                        float* __restrict__ relay,
                                                        unsigned short* __restrict__ yb) {
  int b = blockIdx.x, t = threadIdx.x;
  float s = 0.f;
#pragma unroll
  for (int ch = 0; ch < 8; ch++) s += part[((size_t)(b * 8 + ch)) * 256 + t];
  s *= (1.0f / 512.0f);
  relay[b * 256 + t] = s;
  yb[((size_t)b * LP1) * 256 + t] = f2bf(s);
}

// rarf: ra1/ra2 + rf(+fcb+bqf)
__global__ __launch_bounds__(256) void rarf_kernel(const float* __restrict__ relay,
                                                   const float* __restrict__ a1,
                                                   const float* __restrict__ a2,
                                                   const float* __restrict__ fcw,
                                                   const float* __restrict__ fcb,
                                                   const float* __restrict__ bqf,
                                                   float* __restrict__ ra1,
                                                   float* __restrict__ ra2,
                                                   float* __restrict__ rf) {
  int n = blockIdx.x >> 4, b = blockIdx.x & 15;
  int t = threadIdx.x;
  int lane = t & 63, w = t >> 6;
  __shared__ float rel[256];
  __shared__ float red1[4], red2[4];
  __shared__ float pf_s[8][33];
  rel[t] = relay[b * HH + t];
  __syncthreads();
  float p1 = rel[t] * a1[n * 768 + 257 + 2 * t];
  float p2 = rel[t] * a2[n * 768 + 257 + 2 * t];
#pragma unroll
  for (int o = 32; o; o >>= 1) { p1 += __shfl_xor(p1, o); p2 += __shfl_xor(p2, o); }
  if (lane == 0) { red1[w] = p1; red2[w] = p2; }
  int d = t & 31, seg = t >> 5;
  float pf = 0.f;
  for (int u = 0; u < 32; u++) {
    int k = seg * 32 + u;
    pf = fmaf(rel[k], fcw[((size_t)n * 768 + 257 + 2 * k) * 32 + d], pf);
  }
  pf_s[seg][d] = pf;
  __syncthreads();
  if (t == 0) {
    ra1[n * 16 + b] = red1[0] + red1[1] + red1[2] + red1[3];
    ra2[n * 16 + b] = red2[0] + red2[1] + red2[2] + red2[3];
  }
  if (t < 32) {
    float s = 0.f;
    for (int gg = 0; gg < 8; gg++) s += pf_s[gg][t];
    rf[((size_t)n * 16 + b) * 32 + t] = s + fcb[n * 32 + t] + bqf[n * 32 + t];
  }
}

// ---------------------------------------------------------------------------
// Fused LayerNorm + ei/ej; 16 reduction chains batched for ILP
__global__ __launch_bounds__(256) void lnei_kernel(const float* __restrict__ nodes,
                                                   const float* __restrict__ data,
                                                   const float* __restrict__ g,
                                                   const float* __restrict__ bb,
                                                   const float* __restrict__ w1,
                                                   const float* __restrict__ w2,
                                                   const float* __restrict__ a1,
                                                   const float* __restrict__ a2,
                                                   const float* __restrict__ c1,
                                                   const float* __restrict__ c2,
                                                   const float* __restrict__ ra1,
                                                   const float* __restrict__ ra2,
                                                   unsigned short* __restrict__ xnb,
                                                   float* __restrict__ ei,
                                                   float* __restrict__ ej) {
  int r = blockIdx.x * 4 + (threadIdx.x >> 6);
  int b = r >> 9;
  int lane = threadIdx.x & 63;
  float x[4], dv[4];
#pragma unroll
  for (int u = 0; u < 4; u++) {
    int c = lane + 64 * u;
    x[u] = nodes[(size_t)r * 256 + c];
    dv[u] = data[(size_t)r * 256 + c];
  }
  float s = x[0] + x[1] + x[2] + x[3];
#pragma unroll
  for (int o = 32; o; o >>= 1) s += __shfl_xor(s, o);
  float mean = s * (1.0f / 256.0f);
  float v = 0.f;
#pragma unroll
  for (int u = 0; u < 4; u++) { x[u] -= mean; v = fmaf(x[u], x[u], v); }
#pragma unroll
  for (int o = 32; o; o >>= 1) v += __shfl_xor(v, o);
  float rstd = rsqrtf(v * (1.0f / 256.0f) + 1e-5f);
  float xv[4];
#pragma unroll
  for (int u = 0; u < 4; u++) {
    int c = lane + 64 * u;
    xv[u] = x[u] * rstd * g[c] + bb[c];
    xnb[(size_t)r * 256 + c] = f2bf(xv[u]);
  }
  // partials for all 8 heads first (no reductions yet)
  float s1a[8], s2a[8];
#pragma unroll
  for (int n = 0; n < 8; n++) {
    float s1 = 0.f, s2 = 0.f;
#pragma unroll
    for (int u = 0; u < 4; u++) {
      int c = lane + 64 * u;
      s1 = fmaf(xv[u], w1[n * 256 + c], s1);
      s1 = fmaf(dv[u], a1[n * 768 + 256 + 2 * c], s1);
      s2 = fmaf(xv[u], w2[n * 256 + c], s2);
      s2 = fmaf(dv[u], a2[n * 768 + 256 + 2 * c], s2);
    }
    s1a[n] = s1; s2a[n] = s2;
  }
  // 16 chains interleaved per butterfly step
#pragma unroll
  for (int o = 32; o; o >>= 1) {
#pragma unroll
    for (int n = 0; n < 8; n++) {
      s1a[n] += __shfl_xor(s1a[n], o);
      s2a[n] += __shfl_xor(s2a[n], o);
    }
  }
  if (lane == 0) {
#pragma unroll
    for (int n = 0; n < 8; n++) {
      ei[n * 8192 + r] = s1a[n] + c1[n] + ra1[n * 16 + b];
      ej[n * 8192 + r] = s2a[n] + c2[n] + ra2[n * 16 + b];
    }
  }
}

// ---------------------------------------------------------------------------
// G-GEMM: GT[n][b][d][j] = [xn ; data](row j) @ Bcat col (n*32+d)
__global__ __launch_bounds__(256) void g_gemm_kernel(
    const unsigned short* __restrict__ A1, const unsigned short* __restrict__ A2,
    const unsigned short* __restrict__ Bcat, unsigned short* __restrict__ GT) {
  int tileN = blockIdx.x * 64;
  int tileM = blockIdx.y * 128;
  int t = threadIdx.x;
  int wv = t >> 6, lane = t & 63;
  int lo = lane & 15, quad = lane >> 4;
  int rowBase0 = tileM + wv * 32;
  const unsigned short* ap1[2];
  const unsigned short* ap2[2];
#pragma unroll
  for (int rt = 0; rt < 2; rt++) {
    int arow = rowBase0 + rt * 16 + lo;
    ap1[rt] = A1 + (size_t)arow * 256 + quad * 8;
    ap2[rt] = A2 + (size_t)arow * 256 + quad * 8;
  }
  f32x4 acc[2][4] = {};
  for (int k0 = 0; k0 < 512; k0 += 32) {
    bf16x8 af[2];
#pragma unroll
    for (int rt = 0; rt < 2; rt++)
      af[rt] = (k0 < 256) ? *(const bf16x8*)(ap1[rt] + k0)
                          : *(const bf16x8*)(ap2[rt] + k0 - 256);
#pragma unroll
    for (int ct = 0; ct < 4; ct++) {
      bf16x8 bf_ = *(const bf16x8*)(Bcat + (size_t)(tileN + ct * 16 + lo) * 512 + k0 + quad * 8);
#pragma unroll
      for (int rt = 0; rt < 2; rt++)
        acc[rt][ct] = __builtin_amdgcn_mfma_f32_16x16x32_bf16(af[rt], bf_, acc[rt][ct], 0, 0, 0);
    }
  }
#pragma unroll
  for (int rt = 0; rt < 2; rt++) {
#pragma unroll
    for (int ct = 0; ct < 4; ct++) {
      int co = tileN + ct * 16 + lo;
      int n = co >> 5, d = co & 31;
      int jrow = rowBase0 + rt * 16 + quad * 4;
      int b2 = jrow >> 9, jj = jrow & 511;
      ushort4 pk;
      pk.x = f2bf(acc[rt][ct][0]);
      pk.y = f2bf(acc[rt][ct][1]);
      pk.z = f2bf(acc[rt][ct][2]);
      pk.w = f2bf(acc[rt][ct][3]);
      *(ushort4*)&GT[(((size_t)(n * 16 + b2) * 32 + d) << 9) + jj] = pk;
    }
  }
}

// ---------------------------------------------------------------------------
// MFMA GEMM K=256: mode 1 fc epilogue (nodes fp32 + yb bf16); mode 2 bf16 out
__global__ __launch_bounds__(256) void mfma_gemm_kernel(
    const unsigned short* __restrict__ A, const unsigned short* __restrict__ Bw,
    const float* __restrict__ bias, int Mvalid, int mode,
    float* __restrict__ outF, unsigned short* __restrict__ outB,
    const float* __restrict__ resid, const int* __restrict__ mask,
    unsigned short* __restrict__ yb) {
  int tileN = blockIdx.x * 64;
  int tileM = blockIdx.y * 128;
  int t = threadIdx.x;
  int wv = t >> 6, lane = t & 63;
  int lo = lane & 15, quad = lane >> 4;
  int rowBase0 = tileM + wv * 32;
  const unsigned short* aptr[2];
#pragma unroll
  for (int rt = 0; rt < 2; rt++) {
    int arow = rowBase0 + rt * 16 + lo;
    if (arow >= Mvalid) arow = Mvalid - 1;
    aptr[rt] = A + (size_t)arow * 256 + quad * 8;
  }
  f32x4 acc[2][4] = {};
  for (int k0 = 0; k0 < 256; k0 += 32) {
    bf16x8 af[2];
#pragma unroll
    for (int rt = 0; rt < 2; rt++) af[rt] = *(const bf16x8*)(aptr[rt] + k0);
#pragma unroll
    for (int ct = 0; ct < 4; ct++) {
      bf16x8 bf_ = *(const bf16x8*)(Bw + (size_t)(tileN + ct * 16 + lo) * 256 + k0 + quad * 8);
#pragma unroll
      for (int rt = 0; rt < 2; rt++)
        acc[rt][ct] = __builtin_amdgcn_mfma_f32_16x16x32_bf16(af[rt], bf_, acc[rt][ct], 0, 0, 0);
    }
  }
#pragma unroll
  for (int rt = 0; rt < 2; rt++) {
    int rowBase = rowBase0 + rt * 16;
#pragma unroll
    for (int ct = 0; ct < 4; ct++) {
      int co = tileN + ct * 16 + lo;
      float bv = bias[co];
#pragma unroll
      for (int r = 0; r < 4; r++) {
        int row = rowBase + quad * 4 + r;
        if (row >= Mvalid) continue;
        float v = acc[rt][ct][r] + bv;
        if (mode == 1) {
          v = v > 0.f ? v : 0.01f * v;
          v = (mask[row] != 0) ? resid[(size_t)row * 256 + co] + v : 0.f;
          outF[(size_t)row * 256 + co] = v;
          yb[((size_t)(row + (row >> 9) + 1)) * 256 + co] = f2bf(v);
        } else {
          outB[(size_t)row * 256 + co] = f2bf(v);
        }
      }
    }
  }
}

// ---------------------------------------------------------------------------
// GAT: reduction-free softmax (upper-bound max, MFMA ones-column denominator)
__global__ __launch_bounds__(256) void gat_agg_kernel(
    const unsigned short* __restrict__ GT,
    const float* __restrict__ ei, const float* __restrict__ ej,
    const unsigned char* __restrict__ ep,
    const float* __restrict__ rf,
    unsigned short* __restrict__ tempb) {
  __shared__ unsigned short W[32][512];
  __shared__ float denom_s[32];
  int blk = blockIdx.x;
  int n = blk >> 8;
  int b = (blk >> 4) & 15;
  int i0 = (blk & 15) << 5;
  int t = threadIdx.x;
  int wv = t >> 6, lane = t & 63;
  int lo = lane & 15, quad = lane >> 4;

  // ---- Phase A: unnormalized softmax weights, no per-row reductions
  const float* ejrow = ej + n * 8192 + b * 512;
  float ejv[8];
#pragma unroll
  for (int u = 0; u < 8; u++) ejv[u] = ejrow[lane + 64 * u];
  // block-uniform ej max (all waves load identical ejrow)
  float mm = ejv[0];
#pragma unroll
  for (int u = 1; u < 8; u++) mm = fmaxf(mm, ejv[u]);
#pragma unroll
  for (int o = 32; o; o >>= 1) mm = fmaxf(mm, __shfl_xor(mm, o));

  for (int rr = 0; rr < 8; rr++) {
    int row = wv * 8 + rr;
    float eiv = ei[n * 8192 + b * 512 + i0 + row];
    float M = eiv + mm;
    M = M > 0.f ? M : 0.2f * M;            // lrelu(ei + max ej) >= max_j e
    unsigned pb = ep[(((size_t)(b * 512 + i0 + row)) << 6) + lane];
    int rx = (row & 7) << 3;
#pragma unroll
    for (int u = 0; u < 8; u++) {
      float e = eiv + ejv[u];
      e = e > 0.f ? e : 0.2f * e;
      float w = ((pb >> u) & 1) ? __expf(e - M) : 0.f;
      int col = lane + 64 * u;
      W[row][((col >> 3 << 3) ^ rx) + (col & 7)] = f2bf(w);
    }
  }
  __syncthreads();

  // ---- Phase B: wave (rt, dh); dh==0 also accumulates the denominator
  int rt = wv >> 1, dh = wv & 1;
  int arow = rt * 16 + lo;
  int rx = arow & 7;
  const unsigned short* gtb = GT + (((size_t)(n * 16 + b) * 32) << 9);
  bf16x8 bones;
  {
    short ov = (lo == 0) ? (short)0x3F80 : (short)0;   // bf16 1.0 in column 0
#pragma unroll
    for (int j = 0; j < 8; j++) bones[j] = ov;
  }
  f32x4 acc = {}, accd = {};
  for (int k0 = 0; k0 < 512; k0 += 32) {
    int chunk = (k0 >> 3) + quad;
    bf16x8 a0 = *(const bf16x8*)&W[arow][(chunk ^ rx) << 3];
    bf16x8 bf_ = *(const bf16x8*)(gtb + (((size_t)(dh * 16 + lo)) << 9) + k0 + quad * 8);
    acc = __builtin_amdgcn_mfma_f32_16x16x32_bf16(a0, bf_, acc, 0, 0, 0);
    if (dh == 0)
      accd = __builtin_amdgcn_mfma_f32_16x16x32_bf16(a0, bones, accd, 0, 0, 0);
  }
  if (dh == 0 && lo == 0) {
#pragma unroll
    for (int r = 0; r < 4; r++) denom_s[rt * 16 + quad * 4 + r] = accd[r];
  }
  __syncthreads();
  int d = dh * 16 + lo;
  float base = rf[((size_t)n * 16 + b) * 32 + d];
#pragma unroll
  for (int r = 0; r < 4; r++) {
    int row = rt * 16 + quad * 4 + r;
    float inv = 1.0f / fmaxf(denom_s[row], 1e-35f);
    float v = acc[r] * inv + base;
    v = v > 0.f ? v : expm1f(v);
    tempb[((size_t)(b * 512 + i0 + row)) * 256 + n * 32 + d] = f2bf(v);
  }
}

// ---------------------------------------------------------------------------
// star attention on bf16 kt, q computed in-block from relay
__global__ __launch_bounds__(256) void star_attn_kernel(const float* __restrict__ relay,
                                                        const float* __restrict__ sqT_it,
                                                        const float* __restrict__ sqb_it,
                                                        const unsigned short* __restrict__ ktb,
                                                        const int* __restrict__ mask,
                                                        float* __restrict__ attstar) {
  int b = blockIdx.x >> 3, n = blockIdx.x & 7;
  int t = threadIdx.x;
  int lane = t & 63, w = t >> 6;
  __shared__ float relb[256];
  __shared__ float qv[32];
  __shared__ float pre[LP1];
  __shared__ float red[4];
  __shared__ float par[8][33];
  relb[t] = relay[b * 256 + t];
  __syncthreads();
  {
    int d = t & 31, g = t >> 5;
    float qp = 0.f;
    for (int k = 0; k < 32; k++)
      qp = fmaf(relb[g * 32 + k], sqT_it[(size_t)(g * 32 + k) * 256 + n * 32 + d], qp);
    par[g][d] = qp;
  }
  __syncthreads();
  if (t < 32) {
    float q = 0.f;
#pragma unroll
    for (int gg = 0; gg < 8; gg++) q += par[gg][t];
    qv[t] = q + sqb_it[n * 32 + t];
  }
  __syncthreads();
  const float scale = 0.17677669529663687f;
  for (int l = t; l < LP1; l += 256) {
    bool masked = (l > 0) && (mask[b * LL + l - 1] == 0);
    float p;
    if (masked) p = -3.4e38f;
    else {
      p = 0.f;
      const unsigned short* krow = ktb + ((size_t)b * LP1 + l) * 256 + n * 32;
#pragma unroll
      for (int d = 0; d < 32; d++) p = fmaf(qv[d], bf2f(krow[d]), p);
      p *= scale;
    }
    pre[l] = p;
  }
  __syncthreads();
  float m = -3.4e38f;
  for (int l = t; l < LP1; l += 256) m = fmaxf(m, pre[l]);
#pragma unroll
  for (int o = 32; o; o >>= 1) m = fmaxf(m, __shfl_xor(m, o));
  if (lane == 0) red[w] = m;
  __syncthreads();
  m = fmaxf(fmaxf(red[0], red[1]), fmaxf(red[2], red[3]));
  __syncthreads();
  float s = 0.f;
  for (int l = t; l < LP1; l += 256) {
    float wv = __expf(pre[l] - m);
    pre[l] = wv;
    s += wv;
  }
#pragma unroll
  for (int o = 32; o; o >>= 1) s += __shfl_xor(s, o);
  if (lane == 0) red[w] = s;
  __syncthreads();
  float denom = red[0] + red[1] + red[2] + red[3];
  int d = t & 31, g = t >> 5;
  float acc = 0.f;
  for (int l = g; l < LP1; l += 8)
    acc = fmaf(pre[l], bf2f(ktb[((size_t)b * LP1 + l) * 256 + n * 32 + d]), acc);
  par[g][d] = acc;
  __syncthreads();
  if (t < 32) {
    float a = 0.f;
    for (int gg = 0; gg < 8; gg++) a += par[gg][t];
    attstar[b * 256 + n * 32 + t] = a / denom;
  }
}

// ---------------------------------------------------------------------------
// relay = lrelu(atts @ soT + sob); writes relay fp32 + yb bf16 relay row
__global__ __launch_bounds__(256) void so_update_kernel(const float* __restrict__ atts,
                                                        const float* __restrict__ soT_it,
                                                        const float* __restrict__ sob_it,
                                                        float* __restrict__ relay,
                                                        unsigned short* __restrict__ yb) {
  int b = blockIdx.x, t = threadIdx.x;
  __shared__ float xr[256];
  xr[t] = atts[b * 256 + t];
  __syncthreads();
  float acc = 0.f;
  for (int k = 0; k < 256; k++) acc = fmaf(xr[k], soT_it[(size_t)k * 256 + t], acc);
  float v = acc + sob_it[t];
  v = v > 0.f ? v : 0.01f * v;
  relay[b * 256 + t] = v;
  yb[((size_t)b * LP1) * 256 + t] = f2bf(v);
}

// ---------------------------------------------------------------------------
extern "C" void kernel_launch(void* const* d_in, const int* in_sizes, int n_in,
                              void* d_out, int out_size, void* d_ws, size_t ws_size,
                              hipStream_t stream) {
  const float* data  = (const float*)d_in[0];
  const float* WQw   = (const float*)d_in[1];
  const float* WQb   = (const float*)d_in[2];
  const float* a1    = (const float*)d_in[3];
  const float* a2    = (const float*)d_in[4];
  const float* fcw_g = (const float*)d_in[5];
  const float* fcb_g = (const float*)d_in[6];
  const float* ng    = (const float*)d_in[7];
  const float* nb    = (const float*)d_in[8];
  const float* sq_w  = (const float*)d_in[9];
  const float* sq_b  = (const float*)d_in[10];
  const float* sk_w  = (const float*)d_in[11];
  const float* sk_b  = (const float*)d_in[12];
  const float* so_w  = (const float*)d_in[13];
  const float* so_b  = (const float*)d_in[14];
  const float* fc_w  = (const float*)d_in[15];
  const float* fc_b  = (const float*)d_in[16];
  const int*   mask  = (const int*)d_in[17];
  const int*   edge  = (const int*)d_in[18];

  float* nodes = (float*)d_out;
  float* relay = nodes + NODES_ELEMS;

  char* p = (char*)d_ws;
  auto alloc = [&](size_t bytes) -> char* {
    char* r = p; p += (bytes + 255) & ~(size_t)255; return r;
  };
  unsigned short* xnb  = (unsigned short*)alloc((size_t)8192 * 256 * 2);
  unsigned short* datab= (unsigned short*)alloc((size_t)8192 * 256 * 2);
  unsigned short* GT   = (unsigned short*)alloc((size_t)8 * 16 * 32 * 512 * 2);
  unsigned short* tmpb = (unsigned short*)alloc((size_t)8192 * 256 * 2);
  unsigned short* yb   = (unsigned short*)alloc((size_t)8208 * 256 * 2);
  unsigned short* ktb  = (unsigned short*)alloc((size_t)8208 * 256 * 2);
  unsigned char* ep    = (unsigned char*)alloc((size_t)8192 * 64);
  float* ei            = (float*)alloc(65536 * 4);
  float* ej            = (float*)alloc(65536 * 4);
  float* ra1           = (float*)alloc(128 * 4);
  float* ra2           = (float*)alloc(128 * 4);
  float* rf            = (float*)alloc(4096 * 4);
  float* bqf           = (float*)alloc(256 * 4);
  float* w1            = (float*)alloc(2048 * 4);
  float* w2            = (float*)alloc(2048 * 4);
  float* c1            = (float*)alloc(8 * 4);
  float* c2            = (float*)alloc(8 * 4);
  float* rpart         = (float*)alloc(128 * 256 * 4);
  unsigned short* Bcat = (unsigned short*)alloc((size_t)256 * 512 * 2);
  unsigned short* fcwT = (unsigned short*)alloc((size_t)65536 * 2);
  unsigned short* skwb = (unsigned short*)alloc((size_t)131072 * 2);
  float* sqT           = (float*)alloc((size_t)131072 * 4);
  float* soT           = (float*)alloc((size_t)131072 * 4);
  float* atts          = (float*)alloc(4096 * 4);

  // one-time precomputes (8 dispatches)
  copy_cvt_kernel<<<2048, 256, 0, stream>>>(data, nodes, datab);
  w12bqf_kernel<<<8, 256, 0, stream>>>(WQw, WQb, a1, a2, fcw_g, w1, w2, c1, c2, bqf);
  bcat_m1_kernel<<<128, 256, 0, stream>>>(WQw, fcw_g, Bcat);
  prep_misc_kernel<<<1024, 256, 0, stream>>>(fc_w, fcw_g, sk_w, fcwT, Bcat, skwb);
  transpose4_kernel<<<dim3(256, 4), 256, 0, stream>>>(sq_w, so_w, sqT, soT);
  edge_pack_kernel<<<2048, 256, 0, stream>>>(edge, ep);
  relay_part_kernel<<<128, 256, 0, stream>>>(data, rpart);
  relay_fin_kernel<<<BB, 256, 0, stream>>>(rpart, relay, yb);

  for (int it = 0; it < 2; it++) {
    rarf_kernel<<<NHEAD * BB, 256, 0, stream>>>(relay, a1, a2, fcw_g, fcb_g, bqf,
                                                ra1, ra2, rf);
    lnei_kernel<<<2048, 256, 0, stream>>>(nodes, data, ng + it * 256, nb + it * 256,
                                          w1, w2, a1, a2, c1, c2, ra1, ra2,
                                          xnb, ei, ej);
    g_gemm_kernel<<<dim3(4, 64), 256, 0, stream>>>(xnb, datab, Bcat, GT);
    gat_agg_kernel<<<NHEAD * BB * 16, 256, 0, stream>>>(GT, ei, ej, ep, rf, tmpb);
    // nodes = mask ? nodes + lrelu(temp @ fc_w + fc_b) : 0  (+ yb bf16 rows)
    mfma_gemm_kernel<<<dim3(4, 64), 256, 0, stream>>>(tmpb, fcwT, fc_b, 8192, 1,
                                                      nodes, nullptr, nodes, mask, yb);
    // ktb = bf16( y @ sk_wT + sk_b )
    mfma_gemm_kernel<<<dim3(4, 65), 256, 0, stream>>>(yb, skwb + it * 65536,
                                                      sk_b + it * 256, 8208, 2,
                                                      nullptr, ktb, nullptr, nullptr, nullptr);
    star_attn_kernel<<<BB * NHEAD, 256, 0, stream>>>(relay, sqT + it * 65536,
                                                     sq_b + it * 256, ktb, mask, atts);
    so_update_kernel<<<BB, 256, 0, stream>>>(atts, soT + it * 65536, so_b + it * 256,
                                             relay, yb);
  }
}